// Round 3
// baseline (1837.378 us; speedup 1.0000x reference)
//
#include <hip/hip_runtime.h>
#include <hip/hip_bf16.h>
#include <stdint.h>

typedef __bf16 bf16;
typedef __bf16 bf16x8 __attribute__((ext_vector_type(8)));
typedef float  f32x4  __attribute__((ext_vector_type(4)));
typedef float  f32x16 __attribute__((ext_vector_type(16)));

#define MFMA16(a,b,c) __builtin_amdgcn_mfma_f32_16x16x32_bf16(a,b,c,0,0,0)
#define MFMA32(a,b,c) __builtin_amdgcn_mfma_f32_32x32x16_bf16(a,b,c,0,0,0)

__device__ __forceinline__ f32x4 zero4() { f32x4 z; z[0]=0.f; z[1]=0.f; z[2]=0.f; z[3]=0.f; return z; }
__device__ __forceinline__ f32x16 zero16() {
    f32x16 z;
#pragma unroll
    for (int i = 0; i < 16; ++i) z[i] = 0.f;
    return z;
}
__device__ __forceinline__ uint32_t packbf(float lo, float hi) {
    union { bf16 b[2]; uint32_t u; } t;
    t.b[0] = (bf16)lo; t.b[1] = (bf16)hi;
    return t.u;
}
__device__ __forceinline__ bf16x8 frag_from_words(uint32_t w0, uint32_t w1, uint32_t w2, uint32_t w3) {
    union { uint32_t u[4]; bf16x8 v; } t;
    t.u[0] = w0; t.u[1] = w1; t.u[2] = w2; t.u[3] = w3;
    return t.v;
}
// fast GELU (tanh form, max err ~3e-3)
__device__ __forceinline__ float gelu_f(float u) {
    float u2 = u * u;
    float y  = u * (0.7978845608f + 0.0356774081f * u2);
    float e  = __expf(2.0f * y);
    float t  = 1.0f - 2.0f / (e + 1.0f);
    return 0.5f * u * (1.0f + t);
}

// ---------------------------------------------------------------------------
// prep: weights f32 -> bf16 [n][k]; bias matrix transposed bT[h][k][q]
// ---------------------------------------------------------------------------
__global__ __launch_bounds__(512) void prep_kernel(
    const float* __restrict__ wqkv, const float* __restrict__ wproj,
    const float* __restrict__ wfc1, const float* __restrict__ wfc2,
    const float* __restrict__ btab, const int* __restrict__ relidx,
    bf16* __restrict__ wqkvT, bf16* __restrict__ wprojT,
    bf16* __restrict__ wfc1T, bf16* __restrict__ wfc2T,
    float* __restrict__ bT)
{
    int i = blockIdx.x * 512 + threadIdx.x;
    if (i < 49152) { int n = i >> 7, k = i & 127; wqkvT[i] = (bf16)wqkv[k*384 + n]; return; }
    i -= 49152;
    if (i < 16384) { int n = i >> 7, k = i & 127; wprojT[i] = (bf16)wproj[k*128 + n]; return; }
    i -= 16384;
    if (i < 65536) { int n = i >> 7, k = i & 127; wfc1T[i] = (bf16)wfc1[k*512 + n]; return; }
    i -= 65536;
    if (i < 65536) { int n = i >> 9, k = i & 511; wfc2T[i] = (bf16)wfc2[k*128 + n]; return; }
    i -= 65536;
    if (i < 32768) { int h = i >> 12, k = (i >> 6) & 63, q = i & 63;
                     bT[i] = btab[relidx[q*64 + k]*8 + h]; }
}

// ---------------------------------------------------------------------------
// per-window pipeline: h (bf16) already at sm[32768:49152).
// Uses [0:32768) for q/k then o/g ping-pong, [49152:65536) for vT.
// R = f32 residual regs (proj-C-layout), W2 = output regs.
// Ends with __syncthreads() leaving all regions reusable.
// ---------------------------------------------------------------------------
__device__ __forceinline__ void window_pipe(
    char* sm, const int lane, const int wv,
    const float (&R)[4][4], float (&W2)[4][4],
    const float* __restrict__ b_qkv, const float* __restrict__ b_proj,
    const float* __restrict__ ln2_g, const float* __restrict__ ln2_b,
    const float* __restrict__ b_fc1, const float* __restrict__ b_fc2,
    const bf16* __restrict__ wqkvT, const bf16* __restrict__ wprojT,
    const bf16* __restrict__ wfc1T, const bf16* __restrict__ wfc2T,
    const float* __restrict__ bT)
{
    const int l15 = lane & 15;
    const int l4  = (lane >> 4) & 3;
    const int l31 = lane & 31;
    const int hi  = lane >> 5;
    const int fmt = wv >> 1;
    const int fn0 = (wv & 1) * 64;

    // ---------------- QKV GEMM ----------------
    {
        f32x4 aq[4][2], av[4];
#pragma unroll
        for (int mt = 0; mt < 4; ++mt) { aq[mt][0] = zero4(); aq[mt][1] = zero4(); av[mt] = zero4(); }
        const int nq0 = wv * 32;
        const int nv  = 256 + wv*16 + l15;
#pragma unroll
        for (int ks = 0; ks < 4; ++ks) {
            bf16x8 bq0 = *(const bf16x8*)(wqkvT + (nq0      + l15)*128 + ks*32 + l4*8);
            bf16x8 bq1 = *(const bf16x8*)(wqkvT + (nq0 + 16 + l15)*128 + ks*32 + l4*8);
            bf16x8 bv  = *(const bf16x8*)(wqkvT + nv*128 + ks*32 + l4*8);
#pragma unroll
            for (int mt = 0; mt < 4; ++mt) {
                int tok = mt*16 + l15;
                bf16x8 afr = *(const bf16x8*)(sm + 32768 + tok*256 + ((ks*64 + l4*16) ^ ((tok&7)<<4)));
                aq[mt][0] = MFMA16(afr, bq0, aq[mt][0]);
                aq[mt][1] = MFMA16(afr, bq1, aq[mt][1]);
                av[mt]    = MFMA16(afr, bv,  av[mt]);
            }
        }
#pragma unroll
        for (int nt = 0; nt < 2; ++nt) {
            int n = nq0 + nt*16 + l15;
            float bb_ = b_qkv[n];
            char* rb = (n < 128) ? sm : (sm + 16384);
            int c = n & 127;
#pragma unroll
            for (int mt = 0; mt < 4; ++mt)
#pragma unroll
                for (int r = 0; r < 4; ++r) {
                    int tok = mt*16 + l4*4 + r;
                    *(bf16*)(rb + tok*256 + ((2*c) ^ ((tok&7)<<4))) = (bf16)(aq[mt][nt][r] + bb_);
                }
        }
        {
            float bb_ = b_qkv[nv];
            int d = l15;
            char* vb = sm + 49152 + wv*2048 + d*128;
            int sz = (d & 7) << 4;
#pragma unroll
            for (int mt = 0; mt < 4; ++mt) {
                int t0 = mt*16 + l4*4;
                *(uint32_t*)(vb + ((2*t0)     ^ sz)) = packbf(av[mt][0]+bb_, av[mt][1]+bb_);
                *(uint32_t*)(vb + ((2*t0 + 4) ^ sz)) = packbf(av[mt][2]+bb_, av[mt][3]+bb_);
            }
        }
    }
    __syncthreads();

    // ---------------- attention (wave = head), swapped QK^T ----------------
    {
        const float SCALE = 0.35355339059327373f;
        bf16x8 kf[2], qf[2];
#pragma unroll
        for (int tk = 0; tk < 2; ++tk) {
            int tok = tk*32 + l31;
            kf[tk] = *(const bf16x8*)(sm + 16384 + tok*256 + ((wv*32 + hi*16) ^ ((tok&7)<<4)));
            qf[tk] = *(const bf16x8*)(sm +         tok*256 + ((wv*32 + hi*16) ^ ((tok&7)<<4)));
        }
        __syncthreads();   // q/k consumed -> [0:16K) free for o
#pragma unroll
        for (int tq = 0; tq < 2; ++tq) {
            int q = tq*32 + l31;
            f32x16 s0 = MFMA32(kf[0], qf[tq], zero16());
            f32x16 s1 = MFMA32(kf[1], qf[tq], zero16());
            const float* bh = bT + wv*4096 + q;
            float vmax = -3.0e38f;
#pragma unroll
            for (int r = 0; r < 16; ++r) {
                int k0 = (r&3) + 8*((r>>2)&3) + 4*hi;
                s0[r] = s0[r]*SCALE + bh[k0*64];
                s1[r] = s1[r]*SCALE + bh[(k0+32)*64];
                vmax = fmaxf(vmax, fmaxf(s0[r], s1[r]));
            }
            vmax = fmaxf(vmax, __shfl_xor(vmax, 32, 64));
            float ss = 0.f;
#pragma unroll
            for (int r = 0; r < 16; ++r) {
                s0[r] = __expf(s0[r] - vmax);
                s1[r] = __expf(s1[r] - vmax);
                ss += s0[r] + s1[r];
            }
            ss += __shfl_xor(ss, 32, 64);
            float ri = 1.0f / ss;
#pragma unroll
            for (int r = 0; r < 16; ++r) { s0[r] *= ri; s1[r] *= ri; }
            f32x16 Ot = zero16();
#pragma unroll
            for (int ks = 0; ks < 4; ++ks) {
                uint32_t own[4];
#pragma unroll
                for (int i = 0; i < 4; ++i) {
                    const int j = 2*(i&1) + 4*((2*ks + (i>>1)) & 3) + 16*(ks>>1);
                    if (j < 16) own[i] = packbf(s0[j], s0[j+1]);
                    else        own[i] = packbf(s1[j-16], s1[j-15]);
                }
                uint32_t sw0 = __shfl_xor(own[0], 32, 64);
                uint32_t sw1 = __shfl_xor(own[1], 32, 64);
                uint32_t sw2 = __shfl_xor(own[2], 32, 64);
                uint32_t sw3 = __shfl_xor(own[3], 32, 64);
                uint32_t w0 = hi ? sw2    : own[0];
                uint32_t w1 = hi ? sw3    : own[1];
                uint32_t w2 = hi ? own[2] : sw0;
                uint32_t w3 = hi ? own[3] : sw1;
                bf16x8 pf = frag_from_words(w0, w1, w2, w3);
                int dd = l31 & 15;
                bf16x8 vf = *(const bf16x8*)(sm + 49152 + wv*2048 + dd*128
                                             + ((ks*32 + hi*16) ^ ((dd&7)<<4)));
                Ot = MFMA32(vf, pf, Ot);
            }
            // write o rows for this tq
#pragma unroll
            for (int r = 0; r < 8; r += 2) {
                int d = (r&3) + 8*(r>>2) + 4*hi;
                *(uint32_t*)(sm + q*256 + ((2*(wv*16 + d)) ^ ((q&7)<<4))) = packbf(Ot[r], Ot[r+1]);
            }
        }
    }
    __syncthreads();

    // ---------------- proj + residual ----------------
    {
        f32x4 acc[4];
#pragma unroll
        for (int nt = 0; nt < 4; ++nt) acc[nt] = zero4();
#pragma unroll
        for (int ks = 0; ks < 4; ++ks) {
            int tok = fmt*16 + l15;
            bf16x8 afr = *(const bf16x8*)(sm + tok*256 + ((ks*64 + l4*16) ^ ((tok&7)<<4)));
#pragma unroll
            for (int nt = 0; nt < 4; ++nt) {
                int n = fn0 + nt*16 + l15;
                bf16x8 bfr = *(const bf16x8*)(wprojT + n*128 + ks*32 + l4*8);
                acc[nt] = MFMA16(afr, bfr, acc[nt]);
            }
        }
#pragma unroll
        for (int nt = 0; nt < 4; ++nt) {
            float bp = b_proj[fn0 + nt*16 + l15];
#pragma unroll
            for (int r = 0; r < 4; ++r) W2[nt][r] = R[nt][r] + acc[nt][r] + bp;
        }
    }

    // ---------------- LN2 from regs ----------------
    {
        float s[4], s2[4];
#pragma unroll
        for (int r = 0; r < 4; ++r) {
            s[r]  = W2[0][r] + W2[1][r] + W2[2][r] + W2[3][r];
            s2[r] = W2[0][r]*W2[0][r] + W2[1][r]*W2[1][r]
                  + W2[2][r]*W2[2][r] + W2[3][r]*W2[3][r];
#pragma unroll
            for (int m = 1; m < 16; m <<= 1) {
                s[r]  += __shfl_xor(s[r],  m, 64);
                s2[r] += __shfl_xor(s2[r], m, 64);
            }
        }
        float2* scr = (float2*)(sm + 16384);
        if (l15 == 0) {
#pragma unroll
            for (int r = 0; r < 4; ++r) {
                int tok = fmt*16 + l4*4 + r;
                scr[tok*2 + (wv&1)] = make_float2(s[r], s2[r]);
            }
        }
        __syncthreads();
        float mean[4], rstd[4];
#pragma unroll
        for (int r = 0; r < 4; ++r) {
            int tok = fmt*16 + l4*4 + r;
            float2 p = scr[tok*2 + ((wv&1)^1)];
            float tot = s[r] + p.x, tot2 = s2[r] + p.y;
            float m = tot * 0.0078125f;
            mean[r] = m;
            rstd[r] = rsqrtf(tot2*0.0078125f - m*m + 1e-5f);
        }
#pragma unroll
        for (int nt = 0; nt < 4; ++nt) {
            int c = fn0 + nt*16 + l15;
            float gg = ln2_g[c], bb2 = ln2_b[c];
#pragma unroll
            for (int r = 0; r < 4; ++r) {
                int tok = fmt*16 + l4*4 + r;
                *(bf16*)(sm + 32768 + tok*256 + ((2*c) ^ ((tok&7)<<4)))
                    = (bf16)((W2[nt][r] - mean[r]) * rstd[r] * gg + bb2);
            }
        }
    }
    __syncthreads();

    // ---------------- MLP (g ping-pong, fast GELU) ----------------
    {
        f32x4 acc2[4];
#pragma unroll
        for (int nt = 0; nt < 4; ++nt) acc2[nt] = zero4();
#pragma unroll
        for (int c4 = 0; c4 < 4; ++c4) {
            char* gbuf = sm + (c4 & 1) * 16384;
            {
                f32x4 a1[4];
#pragma unroll
                for (int nt = 0; nt < 4; ++nt) a1[nt] = zero4();
#pragma unroll
                for (int ks = 0; ks < 4; ++ks) {
                    int tok = fmt*16 + l15;
                    bf16x8 afr = *(const bf16x8*)(sm + 32768 + tok*256 + ((ks*64 + l4*16) ^ ((tok&7)<<4)));
#pragma unroll
                    for (int nt = 0; nt < 4; ++nt) {
                        int n = c4*128 + fn0 + nt*16 + l15;
                        bf16x8 bfr = *(const bf16x8*)(wfc1T + n*128 + ks*32 + l4*8);
                        a1[nt] = MFMA16(afr, bfr, a1[nt]);
                    }
                }
#pragma unroll
                for (int nt = 0; nt < 4; ++nt) {
                    int cl = fn0 + nt*16 + l15;
                    float b1 = b_fc1[c4*128 + cl];
#pragma unroll
                    for (int r = 0; r < 4; ++r) {
                        int tok = fmt*16 + l4*4 + r;
                        float u = a1[nt][r] + b1;
                        *(bf16*)(gbuf + tok*256 + ((2*cl) ^ ((tok&7)<<4))) = (bf16)gelu_f(u);
                    }
                }
            }
            __syncthreads();
#pragma unroll
            for (int ks = 0; ks < 4; ++ks) {
                int tok = fmt*16 + l15;
                bf16x8 afr = *(const bf16x8*)(gbuf + tok*256 + ((ks*64 + l4*16) ^ ((tok&7)<<4)));
#pragma unroll
                for (int nt = 0; nt < 4; ++nt) {
                    int n = fn0 + nt*16 + l15;
                    bf16x8 bfr = *(const bf16x8*)(wfc2T + n*512 + c4*128 + ks*32 + l4*8);
                    acc2[nt] = MFMA16(afr, bfr, acc2[nt]);
                }
            }
        }
#pragma unroll
        for (int nt = 0; nt < 4; ++nt) {
            float bf_ = b_fc2[fn0 + nt*16 + l15];
#pragma unroll
            for (int r = 0; r < 4; ++r) W2[nt][r] += acc2[nt][r] + bf_;
        }
    }
    __syncthreads();
}

// ---------------------------------------------------------------------------
// fused Swin block: 2 horizontally-adjacent windows per block (full-line HBM IO)
// ---------------------------------------------------------------------------
__global__ __launch_bounds__(512, 4) void swin_fused(
    const float* __restrict__ x,
    const float* __restrict__ ln1_g, const float* __restrict__ ln1_b,
    const float* __restrict__ b_qkv, const float* __restrict__ b_proj,
    const float* __restrict__ ln2_g, const float* __restrict__ ln2_b,
    const float* __restrict__ b_fc1, const float* __restrict__ b_fc2,
    const bf16* __restrict__ wqkvT, const bf16* __restrict__ wprojT,
    const bf16* __restrict__ wfc1T, const bf16* __restrict__ wfc2T,
    const float* __restrict__ bT,
    float* __restrict__ out)
{
    __shared__ __align__(16) char sm[65536];

    const int tid  = threadIdx.x;
    const int lane = tid & 63;
    const int wv   = tid >> 6;
    const int l15  = lane & 15;
    const int l4   = (lane >> 4) & 3;
    const int fmt  = wv >> 1;
    const int fn0h = wv & 1;
    const int fn0  = fn0h * 64;

    // XCD-aware swizzle (2048 % 8 == 0)
    const int wid = ((blockIdx.x & 7) << 8) | (blockIdx.x >> 3);
    const int bb  = wid >> 9;
    const int hw  = (wid >> 4) & 31;
    const int wp  = wid & 15;
    const size_t base = (size_t)bb * 8388608 + (size_t)hw * 2048 + (size_t)wp * 16;
    const float* xw   = x   + base;
    float*       outw = out + base;

    float RA[4][4], RB[4][4];

    // ---------------- P1: stage x in two 64-channel chunks; extract residuals ----------------
#pragma unroll
    for (int half = 0; half < 2; ++half) {
        if (half) __syncthreads();
#pragma unroll
        for (int it = 0; it < 4; ++it) {
            int idx = it*512 + tid;
            int cL = idx >> 5;
            int r8 = (idx >> 2) & 7;
            int q4 = idx & 3;
            f32x4 v = *(const f32x4*)(xw + (size_t)(half*64 + cL)*65536 + r8*256 + q4*4);
            int tok2 = (q4 >> 1)*64 + r8*8 + (q4 & 1)*4;
            *(f32x4*)(sm + cL*512 + ((tok2*4) ^ ((cL & 15) << 4))) = v;
        }
        __syncthreads();
        if (fn0h == half) {
#pragma unroll
            for (int nt = 0; nt < 4; ++nt)
#pragma unroll
                for (int r = 0; r < 4; ++r) {
                    int cL = nt*16 + l15;
                    int tokA = fmt*16 + l4*4 + r;
                    const char* p = sm + cL*512;
                    RA[nt][r] = *(const float*)(p + ((tokA*4)        ^ ((cL&15)<<4)));
                    RB[nt][r] = *(const float*)(p + (((64+tokA)*4)   ^ ((cL&15)<<4)));
                }
        }
    }
    __syncthreads();

    // ---------------- P2: LN1 stats (both windows) from regs; write hA ----------------
    float mA[4], rsA[4], mB[4], rsB[4];
    {
        float2* scr = (float2*)sm;
#pragma unroll
        for (int r = 0; r < 4; ++r) {
            float sA=0.f, qA=0.f, sB=0.f, qB=0.f;
#pragma unroll
            for (int nt = 0; nt < 4; ++nt) {
                sA += RA[nt][r]; qA += RA[nt][r]*RA[nt][r];
                sB += RB[nt][r]; qB += RB[nt][r]*RB[nt][r];
            }
#pragma unroll
            for (int m = 1; m < 16; m <<= 1) {
                sA += __shfl_xor(sA, m, 64); qA += __shfl_xor(qA, m, 64);
                sB += __shfl_xor(sB, m, 64); qB += __shfl_xor(qB, m, 64);
            }
            if (l15 == 0) {
                int tok = fmt*16 + l4*4 + r;
                scr[tok*2 + fn0h]      = make_float2(sA, qA);
                scr[(64+tok)*2 + fn0h] = make_float2(sB, qB);
            }
            mA[r] = sA; rsA[r] = qA; mB[r] = sB; rsB[r] = qB;
        }
        __syncthreads();
#pragma unroll
        for (int r = 0; r < 4; ++r) {
            int tok = fmt*16 + l4*4 + r;
            float2 pA = scr[tok*2 + (fn0h^1)];
            float2 pB = scr[(64+tok)*2 + (fn0h^1)];
            float tA = mA[r] + pA.x, t2A = rsA[r] + pA.y;
            float tB = mB[r] + pB.x, t2B = rsB[r] + pB.y;
            mA[r] = tA * 0.0078125f;
            rsA[r] = rsqrtf(t2A*0.0078125f - mA[r]*mA[r] + 1e-5f);
            mB[r] = tB * 0.0078125f;
            rsB[r] = rsqrtf(t2B*0.0078125f - mB[r]*mB[r] + 1e-5f);
        }
    }
#pragma unroll
    for (int nt = 0; nt < 4; ++nt) {
        int c = fn0 + nt*16 + l15;
        float gg = ln1_g[c], bb1 = ln1_b[c];
#pragma unroll
        for (int r = 0; r < 4; ++r) {
            int tok = fmt*16 + l4*4 + r;
            *(bf16*)(sm + 32768 + tok*256 + ((2*c) ^ ((tok&7)<<4)))
                = (bf16)((RA[nt][r] - mA[r]) * rsA[r] * gg + bb1);
        }
    }
    __syncthreads();

    // ---------------- window A ----------------
    float W2A[4][4], W2B[4][4];
    window_pipe(sm, lane, wv, RA, W2A,
                b_qkv, b_proj, ln2_g, ln2_b, b_fc1, b_fc2,
                wqkvT, wprojT, wfc1T, wfc2T, bT);

    // ---------------- write hB, window B ----------------
#pragma unroll
    for (int nt = 0; nt < 4; ++nt) {
        int c = fn0 + nt*16 + l15;
        float gg = ln1_g[c], bb1 = ln1_b[c];
#pragma unroll
        for (int r = 0; r < 4; ++r) {
            int tok = fmt*16 + l4*4 + r;
            *(bf16*)(sm + 32768 + tok*256 + ((2*c) ^ ((tok&7)<<4)))
                = (bf16)((RB[nt][r] - mB[r]) * rsB[r] * gg + bb1);
        }
    }
    __syncthreads();
    window_pipe(sm, lane, wv, RB, W2B,
                b_qkv, b_proj, ln2_g, ln2_b, b_fc1, b_fc2,
                wqkvT, wprojT, wfc1T, wfc2T, bT);

    // ---------------- P13: dump + coalesced full-line store, two halves ----------------
#pragma unroll
    for (int half = 0; half < 2; ++half) {
        if (half) __syncthreads();
        if (fn0h == half) {
#pragma unroll
            for (int nt = 0; nt < 4; ++nt)
#pragma unroll
                for (int r = 0; r < 4; ++r) {
                    int cL = nt*16 + l15;
                    int tokA = fmt*16 + l4*4 + r;
                    char* p = sm + cL*512;
                    *(float*)(p + ((tokA*4)      ^ ((cL&15)<<4))) = W2A[nt][r];
                    *(float*)(p + (((64+tokA)*4) ^ ((cL&15)<<4))) = W2B[nt][r];
                }
        }
        __syncthreads();
#pragma unroll
        for (int it = 0; it < 4; ++it) {
            int idx = it*512 + tid;
            int cL = idx >> 5;
            int r8 = (idx >> 2) & 7;
            int q4 = idx & 3;
            int tok2 = (q4 >> 1)*64 + r8*8 + (q4 & 1)*4;
            *(f32x4*)(outw + (size_t)(half*64 + cL)*65536 + r8*256 + q4*4)
                = *(const f32x4*)(sm + cL*512 + ((tok2*4) ^ ((cL & 15) << 4)));
        }
    }
}

extern "C" void kernel_launch(void* const* d_in, const int* in_sizes, int n_in,
                              void* d_out, int out_size, void* d_ws, size_t ws_size,
                              hipStream_t stream) {
    const float* x      = (const float*)d_in[0];
    const float* ln1_g  = (const float*)d_in[1];
    const float* ln1_b  = (const float*)d_in[2];
    const float* w_qkv  = (const float*)d_in[3];
    const float* b_qkv  = (const float*)d_in[4];
    const float* w_proj = (const float*)d_in[5];
    const float* b_proj = (const float*)d_in[6];
    const float* btab   = (const float*)d_in[7];
    const float* ln2_g  = (const float*)d_in[8];
    const float* ln2_b  = (const float*)d_in[9];
    const float* w_fc1  = (const float*)d_in[10];
    const float* b_fc1  = (const float*)d_in[11];
    const float* w_fc2  = (const float*)d_in[12];
    const float* b_fc2  = (const float*)d_in[13];
    const int*   relix  = (const int*)d_in[14];
    float* out = (float*)d_out;

    char* ws = (char*)d_ws;                 // needs 524288 B
    bf16*  wqkvT  = (bf16*)(ws);
    bf16*  wprojT = (bf16*)(ws + 98304);
    bf16*  wfc1T  = (bf16*)(ws + 131072);
    bf16*  wfc2T  = (bf16*)(ws + 262144);
    float* bT     = (float*)(ws + 393216);

    prep_kernel<<<dim3(448), dim3(512), 0, stream>>>(
        w_qkv, w_proj, w_fc1, w_fc2, btab, relix,
        wqkvT, wprojT, wfc1T, wfc2T, bT);

    swin_fused<<<dim3(2048), dim3(512), 0, stream>>>(
        x, ln1_g, ln1_b, b_qkv, b_proj, ln2_g, ln2_b, b_fc1, b_fc2,
        wqkvT, wprojT, wfc1T, wfc2T, bT, out);
}

// Round 4
// 801.519 us; speedup vs baseline: 2.2924x; 2.2924x over previous
//
#include <hip/hip_runtime.h>
#include <hip/hip_bf16.h>
#include <stdint.h>

typedef __bf16 bf16;
typedef __bf16 bf16x8 __attribute__((ext_vector_type(8)));
typedef float  f32x4  __attribute__((ext_vector_type(4)));
typedef float  f32x16 __attribute__((ext_vector_type(16)));

#define MFMA16(a,b,c) __builtin_amdgcn_mfma_f32_16x16x32_bf16(a,b,c,0,0,0)
#define MFMA32(a,b,c) __builtin_amdgcn_mfma_f32_32x32x16_bf16(a,b,c,0,0,0)

__device__ __forceinline__ f32x4 zero4() { f32x4 z; z[0]=0.f; z[1]=0.f; z[2]=0.f; z[3]=0.f; return z; }
__device__ __forceinline__ f32x16 zero16() {
    f32x16 z;
#pragma unroll
    for (int i = 0; i < 16; ++i) z[i] = 0.f;
    return z;
}
__device__ __forceinline__ uint32_t packbf(float lo, float hi) {
    union { bf16 b[2]; uint32_t u; } t;
    t.b[0] = (bf16)lo; t.b[1] = (bf16)hi;
    return t.u;
}
__device__ __forceinline__ bf16x8 frag_from_words(uint32_t w0, uint32_t w1, uint32_t w2, uint32_t w3) {
    union { uint32_t u[4]; bf16x8 v; } t;
    t.u[0] = w0; t.u[1] = w1; t.u[2] = w2; t.u[3] = w3;
    return t.v;
}
// fast GELU (tanh form, max err ~3e-3)
__device__ __forceinline__ float gelu_f(float u) {
    float u2 = u * u;
    float y  = u * (0.7978845608f + 0.0356774081f * u2);
    float e  = __expf(2.0f * y);
    float t  = 1.0f - 2.0f / (e + 1.0f);
    return 0.5f * u * (1.0f + t);
}

// ---------------------------------------------------------------------------
// prep: weights f32 -> bf16 [n][k]; bias matrix transposed bT[h][k][q]
// ---------------------------------------------------------------------------
__global__ __launch_bounds__(512) void prep_kernel(
    const float* __restrict__ wqkv, const float* __restrict__ wproj,
    const float* __restrict__ wfc1, const float* __restrict__ wfc2,
    const float* __restrict__ btab, const int* __restrict__ relidx,
    bf16* __restrict__ wqkvT, bf16* __restrict__ wprojT,
    bf16* __restrict__ wfc1T, bf16* __restrict__ wfc2T,
    float* __restrict__ bT)
{
    int i = blockIdx.x * 512 + threadIdx.x;
    if (i < 49152) { int n = i >> 7, k = i & 127; wqkvT[i] = (bf16)wqkv[k*384 + n]; return; }
    i -= 49152;
    if (i < 16384) { int n = i >> 7, k = i & 127; wprojT[i] = (bf16)wproj[k*128 + n]; return; }
    i -= 16384;
    if (i < 65536) { int n = i >> 7, k = i & 127; wfc1T[i] = (bf16)wfc1[k*512 + n]; return; }
    i -= 65536;
    if (i < 65536) { int n = i >> 9, k = i & 511; wfc2T[i] = (bf16)wfc2[k*128 + n]; return; }
    i -= 65536;
    if (i < 32768) { int h = i >> 12, k = (i >> 6) & 63, q = i & 63;
                     bT[i] = btab[relidx[q*64 + k]*8 + h]; }
}

// LayerNorm: reads win f32 from sm[0:32K) (swizzle (t&15)<<4), writes bf16 h
// to dst ([tok][c] bf16, swizzle (tok&7)<<4). 8 threads per token.
__device__ __forceinline__ void ln_to_A(const char* Ws, char* dst,
                                        const float* __restrict__ g,
                                        const float* __restrict__ b, int tid)
{
    const int t = tid >> 3, p = tid & 7;
    const int swzW = (t & 15) << 4;
    float v[16];
    float s = 0.f, s2 = 0.f;
#pragma unroll
    for (int i = 0; i < 4; ++i) {
        f32x4 q = *(const f32x4*)(Ws + t*512 + ((p*64 + i*16) ^ swzW));
#pragma unroll
        for (int e = 0; e < 4; ++e) { float f = q[e]; v[i*4+e] = f; s += f; s2 += f*f; }
    }
#pragma unroll
    for (int m = 1; m < 8; m <<= 1) { s += __shfl_xor(s, m, 64); s2 += __shfl_xor(s2, m, 64); }
    const float mean = s * 0.0078125f;
    const float rs = rsqrtf(s2 * 0.0078125f - mean*mean + 1e-5f);
    const int swzH = (t & 7) << 4;
#pragma unroll
    for (int hlf = 0; hlf < 2; ++hlf) {
        bf16x8 hv;
#pragma unroll
        for (int e = 0; e < 8; ++e) {
            int c = p*16 + hlf*8 + e;
            hv[e] = (bf16)((v[hlf*8+e] - mean) * rs * g[c] + b[c]);
        }
        *(bf16x8*)(dst + t*256 + ((p*32 + hlf*16) ^ swzH)) = hv;
    }
}

// ---------------------------------------------------------------------------
// fused Swin block: 1 window per block, 512 threads (8 waves)
// LDS (64KB):
//  [0:32768)     : x-stage f32 -> q[0:16K)+k[16K:32K) -> o[0:16K)+ln2scr[16K:17K)
//                  -> MLP g ping-pong -> out-stage f32
//  [32768:49152) : h bf16 [tok][c] -> h2 bf16
//  [49152:65536) : vT bf16 [head][d 16][tok 64]
// ---------------------------------------------------------------------------
__global__ __launch_bounds__(512, 2) void swin_fused(
    const float* __restrict__ x,
    const float* __restrict__ ln1_g, const float* __restrict__ ln1_b,
    const float* __restrict__ b_qkv, const float* __restrict__ b_proj,
    const float* __restrict__ ln2_g, const float* __restrict__ ln2_b,
    const float* __restrict__ b_fc1, const float* __restrict__ b_fc2,
    const bf16* __restrict__ wqkvT, const bf16* __restrict__ wprojT,
    const bf16* __restrict__ wfc1T, const bf16* __restrict__ wfc2T,
    const float* __restrict__ bT,
    float* __restrict__ out)
{
    __shared__ __align__(16) char sm[65536];

    const int tid  = threadIdx.x;
    const int lane = tid & 63;
    const int wv   = tid >> 6;
    const int l15  = lane & 15;
    const int l4   = (lane >> 4) & 3;
    const int l31  = lane & 31;
    const int hi   = lane >> 5;
    const int fmt  = wv >> 1;
    const int fn0  = (wv & 1) * 64;

    // XCD-aware swizzle (4096 % 8 == 0)
    const int wid = ((blockIdx.x & 7) << 9) | (blockIdx.x >> 3);
    const int bb  = wid >> 10;
    const int hw  = (wid >> 5) & 31;
    const int wwi = wid & 31;
    const size_t base = (size_t)bb * 8388608 + (size_t)hw * 2048 + (size_t)wwi * 8;
    const float* xw   = x   + base;
    float*       outw = out + base;

    // ---------------- P1: stage x window (dwordx4 loads, scalar LDS scatter) ----------------
#pragma unroll
    for (int it = 0; it < 4; ++it) {
        int idx = it*512 + tid;
        int c = idx >> 4, t2 = idx & 15;
        int row = t2 >> 1, col0 = (t2 & 1) * 4;
        f32x4 v = *(const f32x4*)(xw + (size_t)c*65536 + row*256 + col0);
#pragma unroll
        for (int e = 0; e < 4; ++e) {
            int t = row*8 + col0 + e;
            *(float*)(sm + t*512 + ((c*4) ^ ((t&15)<<4))) = v[e];
        }
    }
    __syncthreads();

    // ---------------- P2: LN1 -> h; win residual -> regs ----------------
    ln_to_A(sm, sm + 32768, ln1_g, ln1_b, tid);
    float win[4][4];
#pragma unroll
    for (int nt = 0; nt < 4; ++nt)
#pragma unroll
        for (int r = 0; r < 4; ++r) {
            int tok = fmt*16 + l4*4 + r;
            int c   = fn0 + nt*16 + l15;
            win[nt][r] = *(const float*)(sm + tok*512 + ((c*4) ^ ((tok&15)<<4)));
        }
    __syncthreads();

    // ---------------- P3: QKV GEMM ----------------
    {
        f32x4 aq[4][2], av[4];
#pragma unroll
        for (int mt = 0; mt < 4; ++mt) { aq[mt][0] = zero4(); aq[mt][1] = zero4(); av[mt] = zero4(); }
        const int nq0 = wv * 32;
        const int nv  = 256 + wv*16 + l15;
#pragma unroll
        for (int ks = 0; ks < 4; ++ks) {
            bf16x8 bq0 = *(const bf16x8*)(wqkvT + (nq0      + l15)*128 + ks*32 + l4*8);
            bf16x8 bq1 = *(const bf16x8*)(wqkvT + (nq0 + 16 + l15)*128 + ks*32 + l4*8);
            bf16x8 bv  = *(const bf16x8*)(wqkvT + nv*128 + ks*32 + l4*8);
#pragma unroll
            for (int mt = 0; mt < 4; ++mt) {
                int tok = mt*16 + l15;
                bf16x8 afr = *(const bf16x8*)(sm + 32768 + tok*256 + ((ks*64 + l4*16) ^ ((tok&7)<<4)));
                aq[mt][0] = MFMA16(afr, bq0, aq[mt][0]);
                aq[mt][1] = MFMA16(afr, bq1, aq[mt][1]);
                av[mt]    = MFMA16(afr, bv,  av[mt]);
            }
        }
#pragma unroll
        for (int nt = 0; nt < 2; ++nt) {
            int n = nq0 + nt*16 + l15;
            float bb_ = b_qkv[n];
            char* rb = (n < 128) ? sm : (sm + 16384);
            int c = n & 127;
#pragma unroll
            for (int mt = 0; mt < 4; ++mt)
#pragma unroll
                for (int r = 0; r < 4; ++r) {
                    int tok = mt*16 + l4*4 + r;
                    *(bf16*)(rb + tok*256 + ((2*c) ^ ((tok&7)<<4))) = (bf16)(aq[mt][nt][r] + bb_);
                }
        }
        {
            float bb_ = b_qkv[nv];
            int d = l15;
            char* vb = sm + 49152 + wv*2048 + d*128;
            int sz = (d & 7) << 4;
#pragma unroll
            for (int mt = 0; mt < 4; ++mt) {
                int t0 = mt*16 + l4*4;
                *(uint32_t*)(vb + ((2*t0)     ^ sz)) = packbf(av[mt][0]+bb_, av[mt][1]+bb_);
                *(uint32_t*)(vb + ((2*t0 + 4) ^ sz)) = packbf(av[mt][2]+bb_, av[mt][3]+bb_);
            }
        }
    }
    __syncthreads();

    // ---------------- P4: attention (wave = head), swapped QK^T, single Ot ----------------
    {
        const float SCALE = 0.35355339059327373f;
        bf16x8 kf[2], qf[2];
#pragma unroll
        for (int tk = 0; tk < 2; ++tk) {
            int tok = tk*32 + l31;
            kf[tk] = *(const bf16x8*)(sm + 16384 + tok*256 + ((wv*32 + hi*16) ^ ((tok&7)<<4)));
            qf[tk] = *(const bf16x8*)(sm +         tok*256 + ((wv*32 + hi*16) ^ ((tok&7)<<4)));
        }
        __syncthreads();   // q/k consumed -> [0:16K) free for o
#pragma unroll
        for (int tq = 0; tq < 2; ++tq) {
            int q = tq*32 + l31;
            f32x16 s0 = MFMA32(kf[0], qf[tq], zero16());
            f32x16 s1 = MFMA32(kf[1], qf[tq], zero16());
            const float* bh = bT + wv*4096 + q;
            float vmax = -3.0e38f;
#pragma unroll
            for (int r = 0; r < 16; ++r) {
                int k0 = (r&3) + 8*((r>>2)&3) + 4*hi;
                s0[r] = s0[r]*SCALE + bh[k0*64];
                s1[r] = s1[r]*SCALE + bh[(k0+32)*64];
                vmax = fmaxf(vmax, fmaxf(s0[r], s1[r]));
            }
            vmax = fmaxf(vmax, __shfl_xor(vmax, 32, 64));
            float ss = 0.f;
#pragma unroll
            for (int r = 0; r < 16; ++r) {
                s0[r] = __expf(s0[r] - vmax);
                s1[r] = __expf(s1[r] - vmax);
                ss += s0[r] + s1[r];
            }
            ss += __shfl_xor(ss, 32, 64);
            float ri = 1.0f / ss;
#pragma unroll
            for (int r = 0; r < 16; ++r) { s0[r] *= ri; s1[r] *= ri; }
            f32x16 Ot = zero16();
#pragma unroll
            for (int ks = 0; ks < 4; ++ks) {
                uint32_t own[4];
#pragma unroll
                for (int i = 0; i < 4; ++i) {
                    const int j = 2*(i&1) + 4*((2*ks + (i>>1)) & 3) + 16*(ks>>1);
                    if (j < 16) own[i] = packbf(s0[j], s0[j+1]);
                    else        own[i] = packbf(s1[j-16], s1[j-15]);
                }
                uint32_t sw0 = __shfl_xor(own[0], 32, 64);
                uint32_t sw1 = __shfl_xor(own[1], 32, 64);
                uint32_t sw2 = __shfl_xor(own[2], 32, 64);
                uint32_t sw3 = __shfl_xor(own[3], 32, 64);
                uint32_t w0 = hi ? sw2    : own[0];
                uint32_t w1 = hi ? sw3    : own[1];
                uint32_t w2 = hi ? own[2] : sw0;
                uint32_t w3 = hi ? own[3] : sw1;
                bf16x8 pf = frag_from_words(w0, w1, w2, w3);
                int dd = l31 & 15;
                bf16x8 vf = *(const bf16x8*)(sm + 49152 + wv*2048 + dd*128
                                             + ((ks*32 + hi*16) ^ ((dd&7)<<4)));
                Ot = MFMA32(vf, pf, Ot);
            }
#pragma unroll
            for (int r = 0; r < 8; r += 2) {
                int d = (r&3) + 8*(r>>2) + 4*hi;
                *(uint32_t*)(sm + q*256 + ((2*(wv*16 + d)) ^ ((q&7)<<4))) = packbf(Ot[r], Ot[r+1]);
            }
        }
    }
    __syncthreads();

    // ---------------- P5: proj + residual ----------------
    float win2[4][4];
    {
        f32x4 acc[4];
#pragma unroll
        for (int nt = 0; nt < 4; ++nt) acc[nt] = zero4();
#pragma unroll
        for (int ks = 0; ks < 4; ++ks) {
            int tok = fmt*16 + l15;
            bf16x8 afr = *(const bf16x8*)(sm + tok*256 + ((ks*64 + l4*16) ^ ((tok&7)<<4)));
#pragma unroll
            for (int nt = 0; nt < 4; ++nt) {
                int n = fn0 + nt*16 + l15;
                bf16x8 bfr = *(const bf16x8*)(wprojT + n*128 + ks*32 + l4*8);
                acc[nt] = MFMA16(afr, bfr, acc[nt]);
            }
        }
#pragma unroll
        for (int nt = 0; nt < 4; ++nt) {
            float bp = b_proj[fn0 + nt*16 + l15];
#pragma unroll
            for (int r = 0; r < 4; ++r) win2[nt][r] = win[nt][r] + acc[nt][r] + bp;
        }
    }

    // ---------------- P6: LN2 from regs ----------------
    {
        float s[4], s2[4];
#pragma unroll
        for (int r = 0; r < 4; ++r) {
            s[r]  = win2[0][r] + win2[1][r] + win2[2][r] + win2[3][r];
            s2[r] = win2[0][r]*win2[0][r] + win2[1][r]*win2[1][r]
                  + win2[2][r]*win2[2][r] + win2[3][r]*win2[3][r];
#pragma unroll
            for (int m = 1; m < 16; m <<= 1) {
                s[r]  += __shfl_xor(s[r],  m, 64);
                s2[r] += __shfl_xor(s2[r], m, 64);
            }
        }
        float2* scr = (float2*)(sm + 16384);
        if (l15 == 0) {
#pragma unroll
            for (int r = 0; r < 4; ++r) {
                int tok = fmt*16 + l4*4 + r;
                scr[tok*2 + (wv&1)] = make_float2(s[r], s2[r]);
            }
        }
        __syncthreads();
        float mean[4], rstd[4];
#pragma unroll
        for (int r = 0; r < 4; ++r) {
            int tok = fmt*16 + l4*4 + r;
            float2 p = scr[tok*2 + ((wv&1)^1)];
            float tot = s[r] + p.x, tot2 = s2[r] + p.y;
            float m = tot * 0.0078125f;
            mean[r] = m;
            rstd[r] = rsqrtf(tot2*0.0078125f - m*m + 1e-5f);
        }
#pragma unroll
        for (int nt = 0; nt < 4; ++nt) {
            int c = fn0 + nt*16 + l15;
            float gg = ln2_g[c], bb2 = ln2_b[c];
#pragma unroll
            for (int r = 0; r < 4; ++r) {
                int tok = fmt*16 + l4*4 + r;
                *(bf16*)(sm + 32768 + tok*256 + ((2*c) ^ ((tok&7)<<4)))
                    = (bf16)((win2[nt][r] - mean[r]) * rstd[r] * gg + bb2);
            }
        }
    }
    __syncthreads();

    // ---------------- P7: MLP (g ping-pong, fast GELU) ----------------
    {
        f32x4 acc2[4];
#pragma unroll
        for (int nt = 0; nt < 4; ++nt) acc2[nt] = zero4();
#pragma unroll
        for (int c4 = 0; c4 < 4; ++c4) {
            char* gbuf = sm + (c4 & 1) * 16384;
            {
                f32x4 a1[4];
#pragma unroll
                for (int nt = 0; nt < 4; ++nt) a1[nt] = zero4();
#pragma unroll
                for (int ks = 0; ks < 4; ++ks) {
                    int tok = fmt*16 + l15;
                    bf16x8 afr = *(const bf16x8*)(sm + 32768 + tok*256 + ((ks*64 + l4*16) ^ ((tok&7)<<4)));
#pragma unroll
                    for (int nt = 0; nt < 4; ++nt) {
                        int n = c4*128 + fn0 + nt*16 + l15;
                        bf16x8 bfr = *(const bf16x8*)(wfc1T + n*128 + ks*32 + l4*8);
                        a1[nt] = MFMA16(afr, bfr, a1[nt]);
                    }
                }
#pragma unroll
                for (int nt = 0; nt < 4; ++nt) {
                    int cl = fn0 + nt*16 + l15;
                    float b1 = b_fc1[c4*128 + cl];
#pragma unroll
                    for (int r = 0; r < 4; ++r) {
                        int tok = fmt*16 + l4*4 + r;
                        float u = a1[nt][r] + b1;
                        *(bf16*)(gbuf + tok*256 + ((2*cl) ^ ((tok&7)<<4))) = (bf16)gelu_f(u);
                    }
                }
            }
            __syncthreads();
#pragma unroll
            for (int ks = 0; ks < 4; ++ks) {
                int tok = fmt*16 + l15;
                bf16x8 afr = *(const bf16x8*)(gbuf + tok*256 + ((ks*64 + l4*16) ^ ((tok&7)<<4)));
#pragma unroll
                for (int nt = 0; nt < 4; ++nt) {
                    int n = fn0 + nt*16 + l15;
                    bf16x8 bfr = *(const bf16x8*)(wfc2T + n*512 + c4*128 + ks*32 + l4*8);
                    acc2[nt] = MFMA16(afr, bfr, acc2[nt]);
                }
            }
        }
#pragma unroll
        for (int nt = 0; nt < 4; ++nt) {
            float bf_ = b_fc2[fn0 + nt*16 + l15];
#pragma unroll
            for (int r = 0; r < 4; ++r) win2[nt][r] += acc2[nt][r] + bf_;
        }
    }
    __syncthreads();   // drain last g reads before overwriting [0:32K)

    // ---------------- P8: dump + dwordx4 writeback ----------------
#pragma unroll
    for (int nt = 0; nt < 4; ++nt)
#pragma unroll
        for (int r = 0; r < 4; ++r) {
            int tok = fmt*16 + l4*4 + r;
            int c   = fn0 + nt*16 + l15;
            *(float*)(sm + tok*512 + ((c*4) ^ ((tok&15)<<4))) = win2[nt][r];
        }
    __syncthreads();
#pragma unroll
    for (int it = 0; it < 4; ++it) {
        int idx = it*512 + tid;
        int c = idx >> 4, t2 = idx & 15;
        int row = t2 >> 1, col0 = (t2 & 1) * 4;
        f32x4 v;
#pragma unroll
        for (int e = 0; e < 4; ++e) {
            int t = row*8 + col0 + e;
            v[e] = *(const float*)(sm + t*512 + ((c*4) ^ ((t&15)<<4)));
        }
        *(f32x4*)(outw + (size_t)c*65536 + row*256 + col0) = v;
    }
}

extern "C" void kernel_launch(void* const* d_in, const int* in_sizes, int n_in,
                              void* d_out, int out_size, void* d_ws, size_t ws_size,
                              hipStream_t stream) {
    const float* x      = (const float*)d_in[0];
    const float* ln1_g  = (const float*)d_in[1];
    const float* ln1_b  = (const float*)d_in[2];
    const float* w_qkv  = (const float*)d_in[3];
    const float* b_qkv  = (const float*)d_in[4];
    const float* w_proj = (const float*)d_in[5];
    const float* b_proj = (const float*)d_in[6];
    const float* btab   = (const float*)d_in[7];
    const float* ln2_g  = (const float*)d_in[8];
    const float* ln2_b  = (const float*)d_in[9];
    const float* w_fc1  = (const float*)d_in[10];
    const float* b_fc1  = (const float*)d_in[11];
    const float* w_fc2  = (const float*)d_in[12];
    const float* b_fc2  = (const float*)d_in[13];
    const int*   relix  = (const int*)d_in[14];
    float* out = (float*)d_out;

    char* ws = (char*)d_ws;                 // needs 524288 B
    bf16*  wqkvT  = (bf16*)(ws);
    bf16*  wprojT = (bf16*)(ws + 98304);
    bf16*  wfc1T  = (bf16*)(ws + 131072);
    bf16*  wfc2T  = (bf16*)(ws + 262144);
    float* bT     = (float*)(ws + 393216);

    prep_kernel<<<dim3(448), dim3(512), 0, stream>>>(
        w_qkv, w_proj, w_fc1, w_fc2, btab, relix,
        wqkvT, wprojT, wfc1T, wfc2T, bT);

    swin_fused<<<dim3(4096), dim3(512), 0, stream>>>(
        x, ln1_g, ln1_b, b_qkv, b_proj, ln2_g, ln2_b, b_fc1, b_fc2,
        wqkvT, wprojT, wfc1T, wfc2T, bT, out);
}

// Round 5
// 715.306 us; speedup vs baseline: 2.5687x; 1.1205x over previous
//
#include <hip/hip_runtime.h>
#include <hip/hip_bf16.h>
#include <stdint.h>

typedef __bf16 bf16;
typedef __bf16 bf16x8 __attribute__((ext_vector_type(8)));
typedef float  f32x4  __attribute__((ext_vector_type(4)));
typedef float  f32x16 __attribute__((ext_vector_type(16)));

#define MFMA16(a,b,c) __builtin_amdgcn_mfma_f32_16x16x32_bf16(a,b,c,0,0,0)
#define MFMA32(a,b,c) __builtin_amdgcn_mfma_f32_32x32x16_bf16(a,b,c,0,0,0)

__device__ __forceinline__ f32x4 zero4() { f32x4 z; z[0]=0.f; z[1]=0.f; z[2]=0.f; z[3]=0.f; return z; }

__device__ __forceinline__ uint32_t packbf(float lo, float hi) {
    union { bf16 b[2]; uint32_t u; } t;
    t.b[0] = (bf16)lo; t.b[1] = (bf16)hi;
    return t.u;
}
__device__ __forceinline__ bf16x8 frag_from_words(uint32_t w0, uint32_t w1, uint32_t w2, uint32_t w3) {
    union { uint32_t u[4]; bf16x8 v; } t;
    t.u[0] = w0; t.u[1] = w1; t.u[2] = w2; t.u[3] = w3;
    return t.v;
}
// fast GELU (tanh form, max err ~3e-3)
__device__ __forceinline__ float gelu_f(float u) {
    float u2 = u * u;
    float y  = u * (0.7978845608f + 0.0356774081f * u2);
    float e  = __expf(2.0f * y);
    float t  = 1.0f - 2.0f / (e + 1.0f);
    return 0.5f * u * (1.0f + t);
}

// ---------------------------------------------------------------------------
// prep: weights f32 -> bf16 [n][k]; bias matrix natural: bN[h][q][k]
// ws layout (bytes):
//   0      : wqkvT  [384][128] bf16   (98304)
//   98304  : wprojT [128][128] bf16   (32768)
//   131072 : wfc1T  [512][128] bf16   (131072)
//   262144 : wfc2T  [128][512] bf16   (131072)
//   393216 : bN     [8][64][64] f32   (131072)   total 524288 B
// ---------------------------------------------------------------------------
__global__ __launch_bounds__(512) void prep_kernel(
    const float* __restrict__ wqkv, const float* __restrict__ wproj,
    const float* __restrict__ wfc1, const float* __restrict__ wfc2,
    const float* __restrict__ btab, const int* __restrict__ relidx,
    bf16* __restrict__ wqkvT, bf16* __restrict__ wprojT,
    bf16* __restrict__ wfc1T, bf16* __restrict__ wfc2T,
    float* __restrict__ bN)
{
    int i = blockIdx.x * 512 + threadIdx.x;
    if (i < 49152) { int n = i >> 7, k = i & 127; wqkvT[i] = (bf16)wqkv[k*384 + n]; return; }
    i -= 49152;
    if (i < 16384) { int n = i >> 7, k = i & 127; wprojT[i] = (bf16)wproj[k*128 + n]; return; }
    i -= 16384;
    if (i < 65536) { int n = i >> 7, k = i & 127; wfc1T[i] = (bf16)wfc1[k*512 + n]; return; }
    i -= 65536;
    if (i < 65536) { int n = i >> 9, k = i & 511; wfc2T[i] = (bf16)wfc2[k*128 + n]; return; }
    i -= 65536;
    if (i < 32768) { int h = i >> 12, q = (i >> 6) & 63, k = i & 63;
                     bN[i] = btab[relidx[q*64 + k]*8 + h]; }
}

// ---------------------------------------------------------------------------
// fused Swin block: 1 window per block, 512 threads (8 waves), 2 blocks/CU
// LDS 64KB = 4 x 16KB regions:
//  A [0:16K)     : x bf16 [tok][c]  (live to proj)    -> g-even -> out-stage lo
//  B [16K:32K)   : h bf16 -> q bf16 (scaled)          -> h2     -> out-stage hi
//  C [32K:48K)   : k bf16 -> o bf16 -> g-odd
//  D [48K:64K)   : vT bf16 [head][d][tok]             -> ln2 scratch
// ---------------------------------------------------------------------------
__global__ __launch_bounds__(512, 4) void swin_fused(
    const float* __restrict__ x,
    const float* __restrict__ ln1_g, const float* __restrict__ ln1_b,
    const float* __restrict__ b_qkv, const float* __restrict__ b_proj,
    const float* __restrict__ ln2_g, const float* __restrict__ ln2_b,
    const float* __restrict__ b_fc1, const float* __restrict__ b_fc2,
    const bf16* __restrict__ wqkvT, const bf16* __restrict__ wprojT,
    const bf16* __restrict__ wfc1T, const bf16* __restrict__ wfc2T,
    const float* __restrict__ bN,
    float* __restrict__ out)
{
    __shared__ __align__(16) char sm[65536];

    const int tid  = threadIdx.x;
    const int lane = tid & 63;
    const int wv   = tid >> 6;
    const int l15  = lane & 15;
    const int l4   = (lane >> 4) & 3;
    const int l31  = lane & 31;
    const int hi   = lane >> 5;
    const int fmt  = wv >> 1;
    const int fn0  = (wv & 1) * 64;

    // XCD-aware swizzle (4096 % 8 == 0)
    const int wid = ((blockIdx.x & 7) << 9) | (blockIdx.x >> 3);
    const int bb  = wid >> 10;
    const int hw  = (wid >> 5) & 31;
    const int wwi = wid & 31;
    const size_t base = (size_t)bb * 8388608 + (size_t)hw * 2048 + (size_t)wwi * 8;
    const float* xw   = x   + base;
    float*       outw = out + base;

    // ---------------- P1: stage x window as bf16 [tok][c] into A ----------------
#pragma unroll
    for (int it = 0; it < 4; ++it) {
        int idx = it*512 + tid;
        int c = idx >> 4, t2 = idx & 15;
        int row = t2 >> 1, col0 = (t2 & 1) * 4;
        f32x4 v = *(const f32x4*)(xw + (size_t)c*65536 + row*256 + col0);
#pragma unroll
        for (int e = 0; e < 4; ++e) {
            int t = row*8 + col0 + e;
            *(bf16*)(sm + t*256 + ((2*c) ^ ((t&7)<<4))) = (bf16)v[e];
        }
    }
    __syncthreads();

    // ---------------- P2: LN1 (reads A bf16) -> h in B ----------------
    {
        const int t = tid >> 3, p = tid & 7;
        const int swz = (t & 7) << 4;
        float vv[16];
        float s = 0.f, s2 = 0.f;
#pragma unroll
        for (int hlf = 0; hlf < 2; ++hlf) {
            bf16x8 xv = *(const bf16x8*)(sm + t*256 + ((p*32 + hlf*16) ^ swz));
#pragma unroll
            for (int e = 0; e < 8; ++e) { float f = (float)xv[e]; vv[hlf*8+e] = f; s += f; s2 += f*f; }
        }
#pragma unroll
        for (int m = 1; m < 8; m <<= 1) { s += __shfl_xor(s, m, 64); s2 += __shfl_xor(s2, m, 64); }
        const float mean = s * 0.0078125f;
        const float rs = rsqrtf(s2 * 0.0078125f - mean*mean + 1e-5f);
#pragma unroll
        for (int hlf = 0; hlf < 2; ++hlf) {
            bf16x8 hv;
#pragma unroll
            for (int e = 0; e < 8; ++e) {
                int c = p*16 + hlf*8 + e;
                hv[e] = (bf16)((vv[hlf*8+e] - mean) * rs * ln1_g[c] + ln1_b[c]);
            }
            *(bf16x8*)(sm + 16384 + t*256 + ((p*32 + hlf*16) ^ swz)) = hv;
        }
    }
    __syncthreads();

    // ---------------- P3: QKV GEMM (h in B -> q in B (scaled), k in C, vT in D) ----------------
    {
        const float SCALE = 0.35355339059327373f;
        f32x4 aq[4][2], av[4];
#pragma unroll
        for (int mt = 0; mt < 4; ++mt) { aq[mt][0] = zero4(); aq[mt][1] = zero4(); av[mt] = zero4(); }
        const int nq0 = wv * 32;
        const int nv  = 256 + wv*16 + l15;
#pragma unroll
        for (int ks = 0; ks < 4; ++ks) {
            bf16x8 bq0 = *(const bf16x8*)(wqkvT + (nq0      + l15)*128 + ks*32 + l4*8);
            bf16x8 bq1 = *(const bf16x8*)(wqkvT + (nq0 + 16 + l15)*128 + ks*32 + l4*8);
            bf16x8 bv  = *(const bf16x8*)(wqkvT + nv*128 + ks*32 + l4*8);
#pragma unroll
            for (int mt = 0; mt < 4; ++mt) {
                int tok = mt*16 + l15;
                bf16x8 afr = *(const bf16x8*)(sm + 16384 + tok*256 + ((ks*64 + l4*16) ^ ((tok&7)<<4)));
                aq[mt][0] = MFMA16(afr, bq0, aq[mt][0]);
                aq[mt][1] = MFMA16(afr, bq1, aq[mt][1]);
                av[mt]    = MFMA16(afr, bv,  av[mt]);
            }
        }
        __syncthreads();   // all h reads done -> B reusable for q
#pragma unroll
        for (int nt = 0; nt < 2; ++nt) {
            int n = nq0 + nt*16 + l15;
            float bb_ = b_qkv[n];
            bool isq = (n < 128);
            char* rb = isq ? (sm + 16384) : (sm + 32768);
            float sc = isq ? SCALE : 1.0f;
            int c = n & 127;
#pragma unroll
            for (int mt = 0; mt < 4; ++mt)
#pragma unroll
                for (int r = 0; r < 4; ++r) {
                    int tok = mt*16 + l4*4 + r;
                    *(bf16*)(rb + tok*256 + ((2*c) ^ ((tok&7)<<4))) = (bf16)((aq[mt][nt][r] + bb_) * sc);
                }
        }
        {
            float bb_ = b_qkv[nv];
            int d = l15;
            char* vb = sm + 49152 + wv*2048 + d*128;
            int sz = (d & 7) << 4;
#pragma unroll
            for (int mt = 0; mt < 4; ++mt) {
                int t0 = mt*16 + l4*4;
                *(uint32_t*)(vb + ((2*t0)     ^ sz)) = packbf(av[mt][0]+bb_, av[mt][1]+bb_);
                *(uint32_t*)(vb + ((2*t0 + 4) ^ sz)) = packbf(av[mt][2]+bb_, av[mt][3]+bb_);
            }
        }
    }
    __syncthreads();

    // ---------------- P4: attention (wave = head), bias as MFMA C-in, no max-sub ----------------
    {
        bf16x8 kf[2];
#pragma unroll
        for (int tk = 0; tk < 2; ++tk) {
            int tok = tk*32 + l31;
            kf[tk] = *(const bf16x8*)(sm + 32768 + tok*256 + ((wv*32 + hi*16) ^ ((tok&7)<<4)));
        }
        __syncthreads();   // k consumed -> C free for o
#pragma unroll
        for (int tq = 0; tq < 2; ++tq) {
            int q = tq*32 + l31;
            bf16x8 qf = *(const bf16x8*)(sm + 16384 + q*256 + ((wv*32 + hi*16) ^ ((q&7)<<4)));
            const float* bq = bN + wv*4096 + q*64 + 4*hi;
            f32x16 s0, s1;
#pragma unroll
            for (int g4 = 0; g4 < 4; ++g4) {
                f32x4 b0 = *(const f32x4*)(bq + g4*8);
                f32x4 b1 = *(const f32x4*)(bq + 32 + g4*8);
#pragma unroll
                for (int e = 0; e < 4; ++e) { s0[g4*4+e] = b0[e]; s1[g4*4+e] = b1[e]; }
            }
            s0 = MFMA32(kf[0], qf, s0);
            s1 = MFMA32(kf[1], qf, s1);
            float ss = 0.f;
#pragma unroll
            for (int r = 0; r < 16; ++r) {
                s0[r] = __expf(s0[r]);
                s1[r] = __expf(s1[r]);
                ss += s0[r] + s1[r];
            }
            ss += __shfl_xor(ss, 32, 64);
            float ri = 1.0f / ss;
#pragma unroll
            for (int r = 0; r < 16; ++r) { s0[r] *= ri; s1[r] *= ri; }
            f32x16 Ot;
#pragma unroll
            for (int i = 0; i < 16; ++i) Ot[i] = 0.f;
#pragma unroll
            for (int ks = 0; ks < 4; ++ks) {
                uint32_t own[4];
#pragma unroll
                for (int i = 0; i < 4; ++i) {
                    const int j = 2*(i&1) + 4*((2*ks + (i>>1)) & 3) + 16*(ks>>1);
                    if (j < 16) own[i] = packbf(s0[j], s0[j+1]);
                    else        own[i] = packbf(s1[j-16], s1[j-15]);
                }
                uint32_t sw0 = __shfl_xor(own[0], 32, 64);
                uint32_t sw1 = __shfl_xor(own[1], 32, 64);
                uint32_t sw2 = __shfl_xor(own[2], 32, 64);
                uint32_t sw3 = __shfl_xor(own[3], 32, 64);
                uint32_t w0 = hi ? sw2    : own[0];
                uint32_t w1 = hi ? sw3    : own[1];
                uint32_t w2 = hi ? own[2] : sw0;
                uint32_t w3 = hi ? own[3] : sw1;
                bf16x8 pf = frag_from_words(w0, w1, w2, w3);
                int dd = l31 & 15;
                bf16x8 vf = *(const bf16x8*)(sm + 49152 + wv*2048 + dd*128
                                             + ((ks*32 + hi*16) ^ ((dd&7)<<4)));
                Ot = MFMA32(vf, pf, Ot);
            }
            // o rows for this tq -> C
#pragma unroll
            for (int r = 0; r < 8; r += 2) {
                int d = (r&3) + 8*(r>>2) + 4*hi;
                *(uint32_t*)(sm + 32768 + q*256 + ((2*(wv*16 + d)) ^ ((q&7)<<4))) = packbf(Ot[r], Ot[r+1]);
            }
        }
    }
    __syncthreads();

    // ---------------- P5: proj + residual (x from A, o from C) ----------------
    float win2[4][4];
    {
        f32x4 acc[4];
#pragma unroll
        for (int nt = 0; nt < 4; ++nt) acc[nt] = zero4();
#pragma unroll
        for (int ks = 0; ks < 4; ++ks) {
            int tok = fmt*16 + l15;
            bf16x8 afr = *(const bf16x8*)(sm + 32768 + tok*256 + ((ks*64 + l4*16) ^ ((tok&7)<<4)));
#pragma unroll
            for (int nt = 0; nt < 4; ++nt) {
                int n = fn0 + nt*16 + l15;
                bf16x8 bfr = *(const bf16x8*)(wprojT + n*128 + ks*32 + l4*8);
                acc[nt] = MFMA16(afr, bfr, acc[nt]);
            }
        }
#pragma unroll
        for (int nt = 0; nt < 4; ++nt) {
            int c = fn0 + nt*16 + l15;
            float bp = b_proj[c];
#pragma unroll
            for (int r = 0; r < 4; ++r) {
                int tok = fmt*16 + l4*4 + r;
                float xr = (float)*(const bf16*)(sm + tok*256 + ((2*c) ^ ((tok&7)<<4)));
                win2[nt][r] = xr + acc[nt][r] + bp;
            }
        }
    }

    // ---------------- P6: LN2 from regs (scratch in D) -> h2 in B ----------------
    {
        float s[4], s2[4];
#pragma unroll
        for (int r = 0; r < 4; ++r) {
            s[r]  = win2[0][r] + win2[1][r] + win2[2][r] + win2[3][r];
            s2[r] = win2[0][r]*win2[0][r] + win2[1][r]*win2[1][r]
                  + win2[2][r]*win2[2][r] + win2[3][r]*win2[3][r];
#pragma unroll
            for (int m = 1; m < 16; m <<= 1) {
                s[r]  += __shfl_xor(s[r],  m, 64);
                s2[r] += __shfl_xor(s2[r], m, 64);
            }
        }
        float2* scr = (float2*)(sm + 49152);
        if (l15 == 0) {
#pragma unroll
            for (int r = 0; r < 4; ++r) {
                int tok = fmt*16 + l4*4 + r;
                scr[tok*2 + (wv&1)] = make_float2(s[r], s2[r]);
            }
        }
        __syncthreads();
        float mean[4], rstd[4];
#pragma unroll
        for (int r = 0; r < 4; ++r) {
            int tok = fmt*16 + l4*4 + r;
            float2 p = scr[tok*2 + ((wv&1)^1)];
            float tot = s[r] + p.x, tot2 = s2[r] + p.y;
            float m = tot * 0.0078125f;
            mean[r] = m;
            rstd[r] = rsqrtf(tot2*0.0078125f - m*m + 1e-5f);
        }
#pragma unroll
        for (int nt = 0; nt < 4; ++nt) {
            int c = fn0 + nt*16 + l15;
            float gg = ln2_g[c], bb2 = ln2_b[c];
#pragma unroll
            for (int r = 0; r < 4; ++r) {
                int tok = fmt*16 + l4*4 + r;
                *(bf16*)(sm + 16384 + tok*256 + ((2*c) ^ ((tok&7)<<4)))
                    = (bf16)((win2[nt][r] - mean[r]) * rstd[r] * gg + bb2);
            }
        }
    }
    __syncthreads();

    // ---------------- P7: MLP (h2 in B; g ping-pong A/C; fast GELU) ----------------
    {
        f32x4 acc2[4];
#pragma unroll
        for (int nt = 0; nt < 4; ++nt) acc2[nt] = zero4();
#pragma unroll
        for (int c4 = 0; c4 < 4; ++c4) {
            char* gbuf = (c4 & 1) ? (sm + 32768) : sm;
            {
                f32x4 a1[4];
#pragma unroll
                for (int nt = 0; nt < 4; ++nt) a1[nt] = zero4();
#pragma unroll
                for (int ks = 0; ks < 4; ++ks) {
                    int tok = fmt*16 + l15;
                    bf16x8 afr = *(const bf16x8*)(sm + 16384 + tok*256 + ((ks*64 + l4*16) ^ ((tok&7)<<4)));
#pragma unroll
                    for (int nt = 0; nt < 4; ++nt) {
                        int n = c4*128 + fn0 + nt*16 + l15;
                        bf16x8 bfr = *(const bf16x8*)(wfc1T + n*128 + ks*32 + l4*8);
                        a1[nt] = MFMA16(afr, bfr, a1[nt]);
                    }
                }
#pragma unroll
                for (int nt = 0; nt < 4; ++nt) {
                    int cl = fn0 + nt*16 + l15;
                    float b1 = b_fc1[c4*128 + cl];
#pragma unroll
                    for (int r = 0; r < 4; ++r) {
                        int tok = fmt*16 + l4*4 + r;
                        float u = a1[nt][r] + b1;
                        *(bf16*)(gbuf + tok*256 + ((2*cl) ^ ((tok&7)<<4))) = (bf16)gelu_f(u);
                    }
                }
            }
            __syncthreads();
#pragma unroll
            for (int ks = 0; ks < 4; ++ks) {
                int tok = fmt*16 + l15;
                bf16x8 afr = *(const bf16x8*)(gbuf + tok*256 + ((ks*64 + l4*16) ^ ((tok&7)<<4)));
#pragma unroll
                for (int nt = 0; nt < 4; ++nt) {
                    int n = fn0 + nt*16 + l15;
                    bf16x8 bfr = *(const bf16x8*)(wfc2T + n*512 + c4*128 + ks*32 + l4*8);
                    acc2[nt] = MFMA16(afr, bfr, acc2[nt]);
                }
            }
        }
#pragma unroll
        for (int nt = 0; nt < 4; ++nt) {
            float bf_ = b_fc2[fn0 + nt*16 + l15];
#pragma unroll
            for (int r = 0; r < 4; ++r) win2[nt][r] += acc2[nt][r] + bf_;
        }
    }
    __syncthreads();   // drain last g reads before overwriting [0:32K)

    // ---------------- P8: dump f32 into [0:32K) + dwordx4 writeback ----------------
#pragma unroll
    for (int nt = 0; nt < 4; ++nt)
#pragma unroll
        for (int r = 0; r < 4; ++r) {
            int tok = fmt*16 + l4*4 + r;
            int c   = fn0 + nt*16 + l15;
            *(float*)(sm + tok*512 + ((c*4) ^ ((tok&15)<<4))) = win2[nt][r];
        }
    __syncthreads();
#pragma unroll
    for (int it = 0; it < 4; ++it) {
        int idx = it*512 + tid;
        int c = idx >> 4, t2 = idx & 15;
        int row = t2 >> 1, col0 = (t2 & 1) * 4;
        f32x4 v;
#pragma unroll
        for (int e = 0; e < 4; ++e) {
            int t = row*8 + col0 + e;
            v[e] = *(const float*)(sm + t*512 + ((c*4) ^ ((t&15)<<4)));
        }
        *(f32x4*)(outw + (size_t)c*65536 + row*256 + col0) = v;
    }
}

extern "C" void kernel_launch(void* const* d_in, const int* in_sizes, int n_in,
                              void* d_out, int out_size, void* d_ws, size_t ws_size,
                              hipStream_t stream) {
    const float* x      = (const float*)d_in[0];
    const float* ln1_g  = (const float*)d_in[1];
    const float* ln1_b  = (const float*)d_in[2];
    const float* w_qkv  = (const float*)d_in[3];
    const float* b_qkv  = (const float*)d_in[4];
    const float* w_proj = (const float*)d_in[5];
    const float* b_proj = (const float*)d_in[6];
    const float* btab   = (const float*)d_in[7];
    const float* ln2_g  = (const float*)d_in[8];
    const float* ln2_b  = (const float*)d_in[9];
    const float* w_fc1  = (const float*)d_in[10];
    const float* b_fc1  = (const float*)d_in[11];
    const float* w_fc2  = (const float*)d_in[12];
    const float* b_fc2  = (const float*)d_in[13];
    const int*   relix  = (const int*)d_in[14];
    float* out = (float*)d_out;

    char* ws = (char*)d_ws;                 // needs 524288 B
    bf16*  wqkvT  = (bf16*)(ws);
    bf16*  wprojT = (bf16*)(ws + 98304);
    bf16*  wfc1T  = (bf16*)(ws + 131072);
    bf16*  wfc2T  = (bf16*)(ws + 262144);
    float* bN     = (float*)(ws + 393216);

    prep_kernel<<<dim3(448), dim3(512), 0, stream>>>(
        w_qkv, w_proj, w_fc1, w_fc2, btab, relix,
        wqkvT, wprojT, wfc1T, wfc2T, bN);

    swin_fused<<<dim3(4096), dim3(512), 0, stream>>>(
        x, ln1_g, ln1_b, b_qkv, b_proj, ln2_g, ln2_b, b_fc1, b_fc2,
        wqkvT, wprojT, wfc1T, wfc2T, bN, out);
}